// Round 3
// baseline (348.015 us; speedup 1.0000x reference)
//
#include <hip/hip_runtime.h>

#define NSEG 511
#define NROWS 8            // rows 8..15 only
#define ROW0 8
#define K0 21              // first needed freq bin
#define KEND 500           // bins k with 20 < k < 500
#define NFREQ 479
#define ACC_STRIDE 512     // padded per-row accumulator stride
#define NBLOCKS (2 * NROWS * NSEG)

// XOR swizzle: permutes the i-digit (bits 2..4) by the j-digit (bits 5..7).
// Keeps bits 0..1 intact (float4 groups stay contiguous), bijective per 32-block.
__device__ __forceinline__ int sw(int i) { return i ^ (((i >> 5) & 7) << 2); }

// Position of bin k after in-place DIF with radices [8,8,8,4]:
// k = 512*k3 + 64*i + 8*j + p  ->  pos = k3 + 4*i + 32*j + 256*p
__device__ __forceinline__ int dr_pos(int k) {
    return ((k >> 9) & 3) + 4 * ((k >> 6) & 7) + 32 * ((k >> 3) & 7) + 256 * (k & 7);
}

__device__ __forceinline__ float2 cmul(float2 a, float2 b) {
    return make_float2(fmaf(a.x, b.x, -a.y * b.y), fmaf(a.x, b.y, a.y * b.x));
}
__device__ __forceinline__ float2 cadd(float2 a, float2 b) { return make_float2(a.x + b.x, a.y + b.y); }
__device__ __forceinline__ float2 csub(float2 a, float2 b) { return make_float2(a.x - b.x, a.y - b.y); }

// In-register 8-point DFT (DIF butterfly), x[r] -> y[p] = sum_r x[r] w8^{rp}
__device__ __forceinline__ void dft8(float2* x) {
    const float C45 = 0.70710678118654752440f;
    float2 t0 = cadd(x[0], x[4]), u0 = csub(x[0], x[4]);
    float2 t1 = cadd(x[1], x[5]), u1 = csub(x[1], x[5]);
    float2 t2 = cadd(x[2], x[6]), u2 = csub(x[2], x[6]);
    float2 t3 = cadd(x[3], x[7]), u3 = csub(x[3], x[7]);
    // even outputs: DFT4 of (t0..t3)
    float2 s0 = cadd(t0, t2), d0 = csub(t0, t2);
    float2 s1 = cadd(t1, t3), d1 = csub(t1, t3);
    // odd outputs: DFT4 of (u0, u1*w8, u2*(-i), u3*w8^3)
    float2 v1 = make_float2(C45 * (u1.x + u1.y), C45 * (u1.y - u1.x));
    float2 v2 = make_float2(u2.y, -u2.x);
    float2 v3 = make_float2(C45 * (u3.y - u3.x), -C45 * (u3.x + u3.y));
    float2 s2 = cadd(u0, v2), d2 = csub(u0, v2);
    float2 s3 = cadd(v1, v3), d3 = csub(v1, v3);
    float2 mid1 = make_float2(d1.y, -d1.x);   // -i * d1
    float2 mid3 = make_float2(d3.y, -d3.x);   // -i * d3
    x[0] = cadd(s0, s1); x[4] = csub(s0, s1);
    x[2] = cadd(d0, mid1); x[6] = csub(d0, mid1);
    x[1] = cadd(s2, s3); x[5] = csub(s2, s3);
    x[3] = cadd(d2, mid3); x[7] = csub(d2, mid3);
}

// y[p] *= W^p with W = e^{i*ang}; 1 sincos + 6 cmuls
__device__ __forceinline__ void twiddle8(float2* x, float ang) {
    float s, c;
    __sincosf(ang, &s, &c);
    float2 w1 = make_float2(c, s);
    float2 w2 = cmul(w1, w1);
    float2 w3 = cmul(w2, w1);
    float2 w4 = cmul(w2, w2);
    float2 w5 = cmul(w4, w1);
    float2 w6 = cmul(w3, w3);
    float2 w7 = cmul(w4, w3);
    x[1] = cmul(x[1], w1); x[2] = cmul(x[2], w2); x[3] = cmul(x[3], w3);
    x[4] = cmul(x[4], w4); x[5] = cmul(x[5], w5); x[6] = cmul(x[6], w6);
    x[7] = cmul(x[7], w7);
}

// One block = one (signal, row, segment). Windowed 4096-pt real FFT via
// register-resident 2048-pt complex FFT, radices [8,8,8,4], 3 LDS exchanges.
// Last block (atomic ticket) performs the final ratio-reduction.
__global__ __launch_bounds__(256)
void psd_kernel(const float* __restrict__ pred,
                const float* __restrict__ target,
                float* __restrict__ acc, int* __restrict__ counter,
                float* __restrict__ out) {
    __shared__ float2 buf[2048];   // 16 KiB
    __shared__ int is_last;

    const int bid = blockIdx.x;
    const int seg = bid % NSEG;
    const int row = (bid / NSEG) % NROWS + ROW0;
    const int sig = bid / (NSEG * NROWS);   // 0 = res (target-pred), 1 = target
    const int tid = threadIdx.x;

    const float2* t2p = (const float2*)target;
    const float2* p2p = (const float2*)pred;

    float2 x[8];

    // ---- load + window directly into registers.
    // Complex point m = (real[2m], real[2m+1]); m = tid + 256*r.
    // Real sample 2m lives at batch row 2*seg + (m>>9), float2 offset row*512 + (m&511).
    // Window: w[2m] = 1 - cos(2*pi*m/2048); w[2m+1] = 1 - cos(2*pi*m/2048 + pi/2048).
    const float WA = 3.06796157577128245e-3f;      // 2*pi/2048
    const float CD = 0.99999882344642529f;         // cos(pi/2048)
    const float SD = 1.53398018628476550e-3f;      // sin(pi/2048)
    #pragma unroll
    for (int r = 0; r < 8; ++r) {
        int idx2 = (2 * seg + (r >> 1)) * 8192 + row * 512 + tid + 256 * (r & 1);
        float2 v = t2p[idx2];
        if (sig == 0) { float2 p = p2p[idx2]; v.x -= p.x; v.y -= p.y; }
        int m = tid + 256 * r;
        float sa, ca;
        __sincosf((float)m * WA, &sa, &ca);
        float w0 = 1.0f - ca;
        float w1 = 1.0f - (ca * CD - sa * SD);
        x[r] = make_float2(v.x * w0, v.y * w1);
    }

    // ---- stage A: radix-8 over stride 256 (q = tid), twiddle W2048^{q*p}
    dft8(x);
    twiddle8(x, (float)tid * -3.06796157577128245e-3f);   // -2*pi/2048
    #pragma unroll
    for (int p = 0; p < 8; ++p) buf[sw(tid + 256 * p)] = x[p];
    __syncthreads();

    // ---- stage B: radix-8 over stride 32 within each 256-subFFT
    const int pb = tid >> 5, q0 = tid & 31;
    const int baseB = q0 + 256 * pb;
    #pragma unroll
    for (int j = 0; j < 8; ++j) x[j] = buf[sw(baseB + 32 * j)];
    dft8(x);
    twiddle8(x, (float)q0 * -2.45436926061702596e-2f);    // -2*pi/256
    #pragma unroll
    for (int j = 0; j < 8; ++j) buf[sw(baseB + 32 * j)] = x[j];
    __syncthreads();

    // ---- stage C: radix-8 over stride 4 within each 32-subFFT
    const int pb2 = tid >> 5, j2 = (tid >> 2) & 7, mq = tid & 3;
    const int baseC = mq + 32 * j2 + 256 * pb2;
    #pragma unroll
    for (int i = 0; i < 8; ++i) x[i] = buf[sw(baseC + 4 * i)];
    dft8(x);
    twiddle8(x, (float)mq * -1.96349540849362077e-1f);    // -2*pi/32
    #pragma unroll
    for (int i = 0; i < 8; ++i) buf[sw(baseC + 4 * i)] = x[i];
    __syncthreads();

    // ---- stage D: 512 length-4 DFTs over contiguous quads (twiddle-free),
    // each thread does 2, via float4 pairs (swizzle keeps quads contiguous).
    float4* b4 = (float4*)buf;
    #pragma unroll
    for (int g = 0; g < 2; ++g) {
        int pbase = sw(4 * (tid + 256 * g));      // == 0 mod 4
        float4 lo = b4[(pbase >> 1)];
        float4 hi = b4[(pbase >> 1) + 1];
        float2 a0 = make_float2(lo.x, lo.y), a1 = make_float2(lo.z, lo.w);
        float2 a2 = make_float2(hi.x, hi.y), a3 = make_float2(hi.z, hi.w);
        float2 S0 = cadd(a0, a2), D0 = csub(a0, a2);
        float2 S1 = cadd(a1, a3), D1 = csub(a1, a3);
        float2 mi = make_float2(D1.y, -D1.x);     // -i * D1
        float2 X0 = cadd(S0, S1), X2 = csub(S0, S1);
        float2 X1 = cadd(D0, mi), X3 = csub(D0, mi);
        b4[(pbase >> 1)]     = make_float4(X0.x, X0.y, X1.x, X1.y);
        b4[(pbase >> 1) + 1] = make_float4(X2.x, X2.y, X3.x, X3.y);
    }
    __syncthreads();

    // ---- untangle real FFT + power + accumulate (bins 21..499)
    #pragma unroll
    for (int rr = 0; rr < 2; ++rr) {
        int k = K0 + tid + 256 * rr;
        if (k < KEND) {
            float2 zk = buf[sw(dr_pos(k))];
            float2 zn = buf[sw(dr_pos(2048 - k))];
            float Ex = 0.5f * (zk.x + zn.x);
            float Ey = 0.5f * (zk.y - zn.y);
            float Ox = 0.5f * (zk.y + zn.y);
            float Oy = -0.5f * (zk.x - zn.x);
            float sn, cs;
            __sincosf(-1.53398078788564123e-3f * (float)k, &sn, &cs);  // -2*pi*k/4096
            float xr = Ex + Ox * cs - Oy * sn;
            float xi = Ey + Ox * sn + Oy * cs;
            float pw = xr * xr + xi * xi;
            atomicAdd(&acc[(sig * NROWS + (row - ROW0)) * ACC_STRIDE + (k - K0)], pw);
        }
    }

    // ---- last block reduces: out = sum(P_res/P_tgt) / 240
    // (dfreq=1, scale=480, mean(last 8)*16 => 2/480 = 1/240; /T cancels in ratio)
    __syncthreads();   // all atomics issued & drained (vmcnt(0) before barrier)
    if (tid == 0) {
        __threadfence();
        int old = atomicAdd(counter, 1);
        is_last = (old == NBLOCKS - 1) ? 1 : 0;
    }
    __syncthreads();
    if (is_last) {
        float sum = 0.0f;
        for (int n = tid; n < NROWS * NFREQ; n += 256) {
            int r = n / NFREQ, k = n % NFREQ;
            float num = __hip_atomic_load(&acc[r * ACC_STRIDE + k],
                                          __ATOMIC_RELAXED, __HIP_MEMORY_SCOPE_AGENT);
            float den = __hip_atomic_load(&acc[(NROWS + r) * ACC_STRIDE + k],
                                          __ATOMIC_RELAXED, __HIP_MEMORY_SCOPE_AGENT);
            sum += num / den;
        }
        float* shf = (float*)buf;
        shf[tid] = sum;
        __syncthreads();
        for (int s2 = 128; s2 > 0; s2 >>= 1) {
            if (tid < s2) shf[tid] += shf[tid + s2];
            __syncthreads();
        }
        if (tid == 0) out[0] = shf[0] * (1.0f / 240.0f);
    }
}

extern "C" void kernel_launch(void* const* d_in, const int* in_sizes, int n_in,
                              void* d_out, int out_size, void* d_ws, size_t ws_size,
                              hipStream_t stream) {
    const float* pred = (const float*)d_in[0];
    const float* target = (const float*)d_in[1];
    float* acc = (float*)d_ws;                         // [2][NROWS][ACC_STRIDE]
    int* counter = (int*)(acc + 2 * NROWS * ACC_STRIDE);

    hipMemsetAsync(d_ws, 0, (2 * NROWS * ACC_STRIDE + 1) * sizeof(float), stream);
    psd_kernel<<<NBLOCKS, 256, 0, stream>>>(pred, target, acc, counter, (float*)d_out);
}